// Round 5
// baseline (11129.900 us; speedup 1.0000x reference)
//
#include <hip/hip_runtime.h>
#include <hip/hip_bf16.h>

typedef _Float16 f16;
typedef _Float16 f16x8 __attribute__((ext_vector_type(8)));
typedef float f32x4 __attribute__((ext_vector_type(4)));

#define T_ 256
#define SC 2048.0f
#define INV_SC (1.0f / 2048.0f)

// ---------------------------------------------------------------------------
// Fragment layouts (all f16)  [unchanged from round 4]:
//   A-buffers (x or h): [mt 4][ks 32][part 2][lane 64][e 8]  (256 KB / step)
//   W-buffer: [nblk 256][ks 64][part 2][lane 64][e 8]        (32 MB / layer)
// ---------------------------------------------------------------------------

__global__ void prepack_x_kernel(const float* __restrict__ x, f16* __restrict__ X0) {
  unsigned int idx = blockIdx.x * 256 + threadIdx.x;  // < 33,554,432
  int e    = idx & 7;
  int l    = (idx >> 3) & 63;
  int part = (idx >> 9) & 1;
  int ks   = (idx >> 10) & 31;
  int mt   = (idx >> 15) & 3;
  int t    = idx >> 17;
  int m = mt * 16 + (l & 15);
  int k = ks * 32 + ((l >> 4) << 3) + e;
  int cc = k >> 9, kw = k & 511;
  float v = x[(((size_t)m * T_ + t) * 512 + kw) * 2 + cc];
  f16 h = (f16)v;
  X0[idx] = part ? (f16)((v - (float)h) * SC) : h;
}

__global__ void prepack_w_kernel(const float* __restrict__ Wri, const float* __restrict__ Wii,
                                 const float* __restrict__ Wrh, const float* __restrict__ Wih,
                                 f16* __restrict__ out) {
  unsigned int idx = blockIdx.x * 256 + threadIdx.x;  // < 16,777,216
  int e    = idx & 7;
  int l    = (idx >> 3) & 63;
  int part = (idx >> 9) & 1;
  int ks   = (idx >> 10) & 63;
  int nblk = idx >> 16;
  int np = nblk * 16 + (l & 15);
  int k  = ks * 32 + ((l >> 4) << 3) + e;
  int j  = np >> 3;
  int g  = (np >> 1) & 3;
  int cc = np & 1;
  int kb = k >> 9, kw = k & 511;
  size_t s = (size_t)(g * 512 + j) * 512 + kw;
  float v;
  if (cc == 0) v = (kb == 0) ? Wri[s] : (kb == 1) ? -Wii[s] : (kb == 2) ? Wrh[s] : -Wih[s];
  else         v = (kb == 0) ? Wii[s] : (kb == 1) ?  Wri[s] : (kb == 2) ? Wih[s] :  Wrh[s];
  f16 h = (f16)v;
  out[idx] = part ? (f16)((v - (float)h) * SC) : h;
}

struct PersistArgs {
  const f16* X0;      // [T][131072] layer-0 x frags
  f16* ys0;           // [T][131072] layer-0 h frags (= layer-1 input)
  f16* ys1;           // 2 slots x [131072]
  const f16* zeroF;   // [131072] zeros
  const f16* W0;      // [256][65536]
  const f16* W1;
  const float *br10, *bi10, *br20, *bi20;
  const float *br11, *bi11, *br21, *bi21;
  float* y;           // (B,T,512,2)
  float* hout;        // (2,B,512,2)
  float* cout;        // (2,B,512,2)
  unsigned* flags;    // [256]
};

// Persistent kernel: 256 blocks x 512 threads, 1 block/CU (LDS-forced).
// Dynamic LDS: W slice 131072 B + reduce buffer 8704 B = 139776 B.
__global__ __launch_bounds__(512) void lstm_persist(PersistArgs a) {
  extern __shared__ char smem_raw[];
  f16* Wl = (f16*)smem_raw;                       // [64][2][512] f16
  float* redf = (float*)(smem_raw + 131072);      // [2][4][16][17] f32

  int nblk = blockIdx.x;
  int tid = threadIdx.x;
  int w = tid >> 6, l = tid & 63;
  int mt = w & 3, kh = w >> 2;
  int n_loc = l & 15, r0 = (l >> 4) * 4;

  // epilogue identity (tid < 128): one (m, j-local) pair
  int em = tid >> 1, ejl = tid & 1;
  int ejg = nblk * 2 + ejl;
  int emt = em >> 4, eml = em & 15;
  int lane_h = ((ejg >> 3) & 3) * 16 + eml;
  int ksr = ejg >> 5;
  size_t basef = (size_t)emt * 32768 + (size_t)lane_h * 8 + (ejg & 7);

  float c_r = 0.f, c_i = 0.f;
  unsigned gen = 0;

  for (int layer = 0; layer < 2; ++layer) {
    // stage this block's W slice into LDS
    const f16* Wg = (layer ? a.W1 : a.W0) + (size_t)nblk * 65536;
    for (int i = tid * 8; i < 65536; i += 4096)
      *reinterpret_cast<f16x8*>(Wl + i) = *reinterpret_cast<const f16x8*>(Wg + i);
    __syncthreads();

    const float* br1 = layer ? a.br11 : a.br10;
    const float* bi1 = layer ? a.bi11 : a.bi10;
    const float* br2 = layer ? a.br21 : a.br20;
    const float* bi2 = layer ? a.bi21 : a.bi20;
    c_r = 0.f; c_i = 0.f;

    for (int t = 0; t < T_; ++t) {
      const f16* Ax = (layer ? a.ys0 : a.X0) + (size_t)t * 131072;
      const f16* Ah = (t == 0) ? a.zeroF
                    : (layer ? a.ys1 + (size_t)((t - 1) & 1) * 131072
                             : a.ys0 + (size_t)(t - 1) * 131072);
      const f16* pa = (kh ? Ah : Ax) + mt * 32768 + l * 8;
      const f16* pb = Wl + kh * 32768 + l * 8;

      f32x4 acc = {0.f, 0.f, 0.f, 0.f}, sacc = {0.f, 0.f, 0.f, 0.f};
#pragma unroll 8
      for (int ks = 0; ks < 32; ++ks) {
        f16x8 ah = *reinterpret_cast<const f16x8*>(pa + ks * 1024);
        f16x8 al = *reinterpret_cast<const f16x8*>(pa + ks * 1024 + 512);
        f16x8 bh = *reinterpret_cast<const f16x8*>(pb + ks * 1024);
        f16x8 bl = *reinterpret_cast<const f16x8*>(pb + ks * 1024 + 512);
        acc  = __builtin_amdgcn_mfma_f32_16x16x32_f16(ah, bh, acc, 0, 0, 0);
        sacc = __builtin_amdgcn_mfma_f32_16x16x32_f16(al, bh, sacc, 0, 0, 0);
        sacc = __builtin_amdgcn_mfma_f32_16x16x32_f16(ah, bl, sacc, 0, 0, 0);
      }
      f32x4 comb = acc + sacc * INV_SC;
#pragma unroll
      for (int r = 0; r < 4; ++r)
        redf[((kh * 4 + mt) * 16 + n_loc) * 17 + r0 + r] = comb[r];
      __syncthreads();

      if (tid < 128) {
        float zr[4], zi[4];
#pragma unroll
        for (int g = 0; g < 4; ++g) {
          int nr = ejl * 8 + g * 2, ni = nr + 1;
          int nb = g * 512 + ejg;
          zr[g] = redf[(emt * 16 + nr) * 17 + eml] + redf[((4 + emt) * 16 + nr) * 17 + eml]
                + br1[nb] + br2[nb];
          zi[g] = redf[(emt * 16 + ni) * 17 + eml] + redf[((4 + emt) * 16 + ni) * 17 + eml]
                + bi1[nb] + bi2[nb];
        }
        float gr[4], gi[4];
#pragma unroll
        for (int g = 0; g < 4; ++g) {
          float mag = sqrtf(zr[g] * zr[g] + zi[g] * zi[g]);
          float fn = (g < 3) ? (1.f / (1.f + __expf(-mag))) : tanhf(mag);
          float s = fn / (mag + 1e-8f);
          gr[g] = zr[g] * s;
          gi[g] = zi[g] * s;
        }
        float cnr = c_r * gr[1] + gr[0] * gr[3];
        float cni = c_i * gi[1] + gi[0] * gi[3];
        c_r = cnr; c_i = cni;
        float mm = sqrtf(cnr * cnr + cni * cni);
        float s = tanhf(mm) / (mm + 1e-8f);
        float dr = cnr * s, di = cni * s;
        float hr = gr[2] * dr - gi[2] * di;
        float him = gi[2] * dr + gr[2] * di;

        f16* Yf = layer ? a.ys1 + (size_t)(t & 1) * 131072 : a.ys0 + (size_t)t * 131072;
        f16 hrh = (f16)hr, hih = (f16)him;
        Yf[basef + (size_t)(ksr * 2 + 0) * 512]        = hrh;
        Yf[basef + (size_t)(ksr * 2 + 1) * 512]        = (f16)((hr - (float)hrh) * SC);
        Yf[basef + (size_t)((16 + ksr) * 2 + 0) * 512] = hih;
        Yf[basef + (size_t)((16 + ksr) * 2 + 1) * 512] = (f16)((him - (float)hih) * SC);

        if (layer == 1) {
          float* yp = a.y + (((size_t)em * T_ + t) * 512 + ejg) * 2;
          yp[0] = hr; yp[1] = him;
        }
        if (t == T_ - 1) {
          float* hp = a.hout + (size_t)layer * 65536 + ((size_t)em * 512 + ejg) * 2;
          hp[0] = hr; hp[1] = him;
          float* cq = a.cout + (size_t)layer * 65536 + ((size_t)em * 512 + ejg) * 2;
          cq[0] = cnr; cq[1] = cni;
        }
      }

      // ---- grid barrier (skip after the very last step) ----
      ++gen;
      if (gen < 512u) {
        __syncthreads();  // all waves' stores at vmcnt(0) before flag release
        if (tid == 0)
          __hip_atomic_store(&a.flags[nblk], gen, __ATOMIC_RELEASE, __HIP_MEMORY_SCOPE_AGENT);
        if (w == 0) {
          const unsigned* fp = a.flags + l * 4;
          for (;;) {
            unsigned f0 = __hip_atomic_load(fp + 0, __ATOMIC_RELAXED, __HIP_MEMORY_SCOPE_AGENT);
            unsigned f1 = __hip_atomic_load(fp + 1, __ATOMIC_RELAXED, __HIP_MEMORY_SCOPE_AGENT);
            unsigned f2 = __hip_atomic_load(fp + 2, __ATOMIC_RELAXED, __HIP_MEMORY_SCOPE_AGENT);
            unsigned f3 = __hip_atomic_load(fp + 3, __ATOMIC_RELAXED, __HIP_MEMORY_SCOPE_AGENT);
            unsigned mn = min(min(f0, f1), min(f2, f3));
            if (__all(mn >= gen)) break;
            __builtin_amdgcn_s_sleep(1);
          }
          // acquire: order subsequent h loads, invalidate stale L1/L2
          (void)__hip_atomic_load(a.flags, __ATOMIC_ACQUIRE, __HIP_MEMORY_SCOPE_AGENT);
        }
        __syncthreads();
      }
    }
  }
}

extern "C" void kernel_launch(void* const* d_in, const int* in_sizes, int n_in,
                              void* d_out, int out_size, void* d_ws, size_t ws_size,
                              hipStream_t stream) {
  const float* x = (const float*)d_in[0];
  char* ws = (char*)d_ws;
  f16* X0    = (f16*)(ws + 0);                     //  64 MB
  f16* ys0   = (f16*)(ws + (size_t)67108864);      //  64 MB
  f16* W0    = (f16*)(ws + (size_t)134217728);     //  32 MB
  f16* W1    = (f16*)(ws + (size_t)167772160);     //  32 MB
  f16* ys1   = (f16*)(ws + (size_t)201326592);     // 512 KB (2 slots)
  f16* zeroF = (f16*)(ws + (size_t)201850880);     // 256 KB zeros
  unsigned* flags = (unsigned*)(ws + (size_t)202113024);  // 1 KB

  hipMemsetAsync(ws + 201850880, 0, 262144 + 1024, stream);

  prepack_x_kernel<<<131072, 256, 0, stream>>>(x, X0);
  prepack_w_kernel<<<65536, 256, 0, stream>>>((const float*)d_in[1], (const float*)d_in[2],
                                              (const float*)d_in[5], (const float*)d_in[6], W0);
  prepack_w_kernel<<<65536, 256, 0, stream>>>((const float*)d_in[9], (const float*)d_in[10],
                                              (const float*)d_in[13], (const float*)d_in[14], W1);

  float* y = (float*)d_out;
  PersistArgs pa;
  pa.X0 = X0; pa.ys0 = ys0; pa.ys1 = ys1; pa.zeroF = zeroF;
  pa.W0 = W0; pa.W1 = W1;
  pa.br10 = (const float*)d_in[3];  pa.bi10 = (const float*)d_in[4];
  pa.br20 = (const float*)d_in[7];  pa.bi20 = (const float*)d_in[8];
  pa.br11 = (const float*)d_in[11]; pa.bi11 = (const float*)d_in[12];
  pa.br21 = (const float*)d_in[15]; pa.bi21 = (const float*)d_in[16];
  pa.y = y; pa.hout = y + 16777216; pa.cout = y + 16777216 + 131072;
  pa.flags = flags;

  static bool attr_set = false;
  if (!attr_set) {
    hipFuncSetAttribute((const void*)lstm_persist,
                        hipFuncAttributeMaxDynamicSharedMemorySize, 139776);
    attr_set = true;
  }
  void* kargs[] = { &pa };
  hipLaunchCooperativeKernel((const void*)lstm_persist, dim3(256), dim3(512),
                             kargs, 139776, stream);
}

// Round 6
// 6051.239 us; speedup vs baseline: 1.8393x; 1.8393x over previous
//
#include <hip/hip_runtime.h>
#include <hip/hip_bf16.h>

typedef _Float16 f16;
typedef _Float16 f16x8 __attribute__((ext_vector_type(8)));
typedef float f32x4 __attribute__((ext_vector_type(4)));

#define T_ 256
#define SC 2048.0f
#define INV_SC (1.0f / 2048.0f)

// ---------------------------------------------------------------------------
// Fragment layouts (all f16), unchanged from rounds 4/5:
//   A-buffers (x or h): [mt 4][ks 32][part 2][lane 64][e 8]  (256 KB / step)
//     element = A[mt*16+(l&15)][ks*32+(l>>4)*8+e], part 0=hi 1=lo*SC
//   W-buffer: [nblk 256][ks 64][part 2][lane 64][e 8]        (32 MB / layer)
//     k 0..1023 = x-part (ks 0..31), k 1024..2047 = h-part (ks 32..63)
// ---------------------------------------------------------------------------

__global__ void prepack_x_kernel(const float* __restrict__ x, f16* __restrict__ X0) {
  unsigned int idx = blockIdx.x * 256 + threadIdx.x;  // < 33,554,432
  int e    = idx & 7;
  int l    = (idx >> 3) & 63;
  int part = (idx >> 9) & 1;
  int ks   = (idx >> 10) & 31;
  int mt   = (idx >> 15) & 3;
  int t    = idx >> 17;
  int m = mt * 16 + (l & 15);
  int k = ks * 32 + ((l >> 4) << 3) + e;
  int cc = k >> 9, kw = k & 511;
  float v = x[(((size_t)m * T_ + t) * 512 + kw) * 2 + cc];
  f16 h = (f16)v;
  X0[idx] = part ? (f16)((v - (float)h) * SC) : h;
}

__global__ void prepack_w_kernel(const float* __restrict__ Wri, const float* __restrict__ Wii,
                                 const float* __restrict__ Wrh, const float* __restrict__ Wih,
                                 f16* __restrict__ out) {
  unsigned int idx = blockIdx.x * 256 + threadIdx.x;  // < 16,777,216
  int e    = idx & 7;
  int l    = (idx >> 3) & 63;
  int part = (idx >> 9) & 1;
  int ks   = (idx >> 10) & 63;
  int nblk = idx >> 16;
  int np = nblk * 16 + (l & 15);
  int k  = ks * 32 + ((l >> 4) << 3) + e;
  int j  = np >> 3;
  int g  = (np >> 1) & 3;
  int cc = np & 1;
  int kb = k >> 9, kw = k & 511;
  size_t s = (size_t)(g * 512 + j) * 512 + kw;
  float v;
  if (cc == 0) v = (kb == 0) ? Wri[s] : (kb == 1) ? -Wii[s] : (kb == 2) ? Wrh[s] : -Wih[s];
  else         v = (kb == 0) ? Wii[s] : (kb == 1) ?  Wri[s] : (kb == 2) ? Wih[s] :  Wrh[s];
  f16 h = (f16)v;
  out[idx] = part ? (f16)((v - (float)h) * SC) : h;
}

struct PersistArgs {
  const f16* X0;      // layer-0 x frags [T][131072]
  f16* X0w;           // same buffer, writable: layer-1 h history (X0 dead in layer 1)
  f16* ys0;           // layer-0 h frags [T][131072] (= layer-1 x input)
  const f16* zeroF;   // [131072] zeros
  const f16* W0;      // [256][65536]
  const f16* W1;
  const float *br10, *bi10, *br20, *bi20;
  const float *br11, *bi11, *br21, *bi21;
  float* y;           // (B,T,512,2)
  float* hout;        // (2,B,512,2)
  float* cout;        // (2,B,512,2)
  unsigned* flags;    // [256]
};

// Persistent kernel: 256 blocks x 1024 threads (16 waves = 4 mt x 4 K-quarters).
// Dynamic LDS: W 131072 + redf 17408 + stage 1024 = 149504 B -> 1 block/CU.
// Flush-free barrier: h written via relaxed agent-scope u32 atomics (write-through
// to MALL), vmcnt-drained before a relaxed flag store; readers poll relaxed flags
// then PLAIN-load h (every h address is write-once-fresh, so no stale L2 lines;
// one acquire-inv only at the layer transition to make the X0-buffer reuse safe).
__global__ __launch_bounds__(1024, 4) void lstm_persist(PersistArgs a) {
  extern __shared__ char smem[];
  f16* Wl = (f16*)smem;                                    // 131072 B
  float* redf = (float*)(smem + 131072);                   // [4 kq][4 mt][16][17] f32
  unsigned short* stg = (unsigned short*)(smem + 148480);  // [64 m][4 plane][2 jl] u16

  int nblk = blockIdx.x;
  int tid = threadIdx.x;
  int w = tid >> 6, l = tid & 63;
  int mt = w & 3, kq = w >> 2;
  int n_loc = l & 15, r0 = (l >> 4) * 4;

  // epilogue identity (tid < 128): one (m, j-local) pair
  int em = tid >> 1, ejl = tid & 1;
  int ejg = nblk * 2 + ejl;
  int emt = em >> 4, eml = em & 15;

  float c_r = 0.f, c_i = 0.f;
  unsigned round = 0;

  for (int layer = 0; layer < 2; ++layer) {
    const f16* Wg = (layer ? a.W1 : a.W0) + (size_t)nblk * 65536;
    for (int i = tid * 8; i < 65536; i += 8192)
      *reinterpret_cast<f16x8*>(Wl + i) = *reinterpret_cast<const f16x8*>(Wg + i);
    __syncthreads();

    const float* br1 = layer ? a.br11 : a.br10;
    const float* bi1 = layer ? a.bi11 : a.bi10;
    const float* br2 = layer ? a.br21 : a.br20;
    const float* bi2 = layer ? a.bi21 : a.bi20;
    c_r = 0.f; c_i = 0.f;

    for (int t = 0; t < T_; ++t) {
      const f16* Ax = (layer ? (const f16*)a.ys0 : a.X0) + (size_t)t * 131072;
      const f16* Ahb = layer ? (const f16*)a.X0w : (const f16*)a.ys0;
      const f16* Ah = (t == 0) ? a.zeroF : (Ahb + (size_t)(t - 1) * 131072);

      const f16* pa = ((kq < 2) ? Ax : Ah) + mt * 32768 + (kq & 1) * 16384 + l * 8;
      const f16* pb = Wl + kq * 16384 + l * 8;

      f32x4 acc = {0.f, 0.f, 0.f, 0.f}, sacc = {0.f, 0.f, 0.f, 0.f};
#pragma unroll 8
      for (int ks = 0; ks < 16; ++ks) {
        f16x8 ah = *reinterpret_cast<const f16x8*>(pa + ks * 1024);
        f16x8 al = *reinterpret_cast<const f16x8*>(pa + ks * 1024 + 512);
        f16x8 bh = *reinterpret_cast<const f16x8*>(pb + ks * 1024);
        f16x8 bl = *reinterpret_cast<const f16x8*>(pb + ks * 1024 + 512);
        acc  = __builtin_amdgcn_mfma_f32_16x16x32_f16(ah, bh, acc, 0, 0, 0);
        sacc = __builtin_amdgcn_mfma_f32_16x16x32_f16(al, bh, sacc, 0, 0, 0);
        sacc = __builtin_amdgcn_mfma_f32_16x16x32_f16(ah, bl, sacc, 0, 0, 0);
      }
      f32x4 comb = acc + sacc * INV_SC;
#pragma unroll
      for (int r = 0; r < 4; ++r)
        redf[((kq * 4 + mt) * 16 + n_loc) * 17 + r0 + r] = comb[r];
      __syncthreads();

      if (tid < 128) {
        float zr[4], zi[4];
#pragma unroll
        for (int g = 0; g < 4; ++g) {
          int nr = ejl * 8 + g * 2, ni = nr + 1;
          int nb = g * 512 + ejg;
          zr[g] = redf[((0 + emt) * 16 + nr) * 17 + eml] + redf[((4 + emt) * 16 + nr) * 17 + eml]
                + redf[((8 + emt) * 16 + nr) * 17 + eml] + redf[((12 + emt) * 16 + nr) * 17 + eml]
                + br1[nb] + br2[nb];
          zi[g] = redf[((0 + emt) * 16 + ni) * 17 + eml] + redf[((4 + emt) * 16 + ni) * 17 + eml]
                + redf[((8 + emt) * 16 + ni) * 17 + eml] + redf[((12 + emt) * 16 + ni) * 17 + eml]
                + bi1[nb] + bi2[nb];
        }
        float gr[4], gi[4];
#pragma unroll
        for (int g = 0; g < 4; ++g) {
          float mag = sqrtf(zr[g] * zr[g] + zi[g] * zi[g]);
          float fn = (g < 3) ? (1.f / (1.f + __expf(-mag))) : tanhf(mag);
          float s = fn / (mag + 1e-8f);
          gr[g] = zr[g] * s;
          gi[g] = zi[g] * s;
        }
        float cnr = c_r * gr[1] + gr[0] * gr[3];
        float cni = c_i * gi[1] + gi[0] * gi[3];
        c_r = cnr; c_i = cni;
        float mm = sqrtf(cnr * cnr + cni * cni);
        float s = tanhf(mm) / (mm + 1e-8f);
        float dr = cnr * s, di = cni * s;
        float hr = gr[2] * dr - gi[2] * di;
        float him = gi[2] * dr + gr[2] * di;

        f16 hrh = (f16)hr, hih = (f16)him;
        stg[(em * 4 + 0) * 2 + ejl] = __builtin_bit_cast(unsigned short, hrh);
        stg[(em * 4 + 1) * 2 + ejl] = __builtin_bit_cast(unsigned short, (f16)((hr - (float)hrh) * SC));
        stg[(em * 4 + 2) * 2 + ejl] = __builtin_bit_cast(unsigned short, hih);
        stg[(em * 4 + 3) * 2 + ejl] = __builtin_bit_cast(unsigned short, (f16)((him - (float)hih) * SC));

        if (layer == 1) {
          float* yp = a.y + (((size_t)em * T_ + t) * 512 + ejg) * 2;
          yp[0] = hr; yp[1] = him;
        }
        if (t == T_ - 1) {
          float* hp = a.hout + (size_t)layer * 65536 + ((size_t)em * 512 + ejg) * 2;
          hp[0] = hr; hp[1] = him;
          float* cq = a.cout + (size_t)layer * 65536 + ((size_t)em * 512 + ejg) * 2;
          cq[0] = cnr; cq[1] = cni;
        }
      }
      __syncthreads();  // stage ready

      if (tid < 128) {
        // packed u32 agent-scope stores of h-frags (write-through to MALL)
        int m2 = tid >> 1, pp = tid & 1;
        int mt_h = m2 >> 4, lb = m2 & 15;
        f16* Yb = (layer ? a.X0w : a.ys0) + (size_t)t * 131072;
        unsigned* Y32 = (unsigned*)Yb;
#pragma unroll
        for (int pi = 0; pi < 2; ++pi) {
          int p = 2 * pp + pi;
          int k = ((p >> 1) << 9) + 2 * nblk;   // r: k=jg0, i: k=512+jg0 (jg0 even)
          int part = p & 1;
          int ks = k >> 5;
          int lane_h = lb + 16 * ((k >> 3) & 3);
          int e = k & 7;
          int idx = ((mt_h * 32 + ks) * 2 + part) * 512 + lane_h * 8 + e;  // even
          unsigned v = (unsigned)stg[(m2 * 4 + p) * 2 + 0]
                     | ((unsigned)stg[(m2 * 4 + p) * 2 + 1] << 16);
          __hip_atomic_store(&Y32[idx >> 1], v, __ATOMIC_RELAXED, __HIP_MEMORY_SCOPE_AGENT);
        }
      }

      // ---- flush-free grid barrier (skip after the very last step) ----
      ++round;
      if (round < 512u) {
        asm volatile("s_waitcnt vmcnt(0)" ::: "memory");  // drain this wave's stores
        __syncthreads();
        if (tid == 0)
          __hip_atomic_store(&a.flags[nblk], round, __ATOMIC_RELAXED, __HIP_MEMORY_SCOPE_AGENT);
        if (w == 0) {
          const unsigned* fp = a.flags + l * 4;
          for (;;) {
            unsigned f0 = __hip_atomic_load(fp + 0, __ATOMIC_RELAXED, __HIP_MEMORY_SCOPE_AGENT);
            unsigned f1 = __hip_atomic_load(fp + 1, __ATOMIC_RELAXED, __HIP_MEMORY_SCOPE_AGENT);
            unsigned f2 = __hip_atomic_load(fp + 2, __ATOMIC_RELAXED, __HIP_MEMORY_SCOPE_AGENT);
            unsigned f3 = __hip_atomic_load(fp + 3, __ATOMIC_RELAXED, __HIP_MEMORY_SCOPE_AGENT);
            unsigned mn = min(min(f0, f1), min(f2, f3));
            if (__all(mn >= round)) break;
            __builtin_amdgcn_s_sleep(1);
          }
          asm volatile("" ::: "memory");
        }
        __syncthreads();
        if (round == 256u) {
          // one-time L1+L2 invalidate at the layer transition: makes reuse of the
          // X0 buffer (read as x in layer 0, rewritten as h-history in layer 1) safe.
          (void)__hip_atomic_load(a.flags, __ATOMIC_ACQUIRE, __HIP_MEMORY_SCOPE_AGENT);
        }
      }
    }
  }
}

extern "C" void kernel_launch(void* const* d_in, const int* in_sizes, int n_in,
                              void* d_out, int out_size, void* d_ws, size_t ws_size,
                              hipStream_t stream) {
  const float* x = (const float*)d_in[0];
  char* ws = (char*)d_ws;
  f16* X0    = (f16*)(ws + 0);                     //  64 MB
  f16* ys0   = (f16*)(ws + (size_t)67108864);      //  64 MB
  f16* W0    = (f16*)(ws + (size_t)134217728);     //  32 MB
  f16* W1    = (f16*)(ws + (size_t)167772160);     //  32 MB
  f16* zeroF = (f16*)(ws + (size_t)201326592);     // 256 KB zeros
  unsigned* flags = (unsigned*)(ws + (size_t)201588736);  // 1 KB

  hipMemsetAsync(ws + 201326592, 0, 262144 + 1024, stream);

  prepack_x_kernel<<<131072, 256, 0, stream>>>(x, X0);
  prepack_w_kernel<<<65536, 256, 0, stream>>>((const float*)d_in[1], (const float*)d_in[2],
                                              (const float*)d_in[5], (const float*)d_in[6], W0);
  prepack_w_kernel<<<65536, 256, 0, stream>>>((const float*)d_in[9], (const float*)d_in[10],
                                              (const float*)d_in[13], (const float*)d_in[14], W1);

  float* y = (float*)d_out;
  PersistArgs pa;
  pa.X0 = X0; pa.X0w = X0; pa.ys0 = ys0; pa.zeroF = zeroF;
  pa.W0 = W0; pa.W1 = W1;
  pa.br10 = (const float*)d_in[3];  pa.bi10 = (const float*)d_in[4];
  pa.br20 = (const float*)d_in[7];  pa.bi20 = (const float*)d_in[8];
  pa.br11 = (const float*)d_in[11]; pa.bi11 = (const float*)d_in[12];
  pa.br21 = (const float*)d_in[15]; pa.bi21 = (const float*)d_in[16];
  pa.y = y; pa.hout = y + 16777216; pa.cout = y + 16777216 + 131072;
  pa.flags = flags;

  static bool attr_set = false;
  if (!attr_set) {
    hipFuncSetAttribute((const void*)lstm_persist,
                        hipFuncAttributeMaxDynamicSharedMemorySize, 149504);
    attr_set = true;
  }
  void* kargs[] = { &pa };
  hipLaunchCooperativeKernel((const void*)lstm_persist, dim3(256), dim3(1024),
                             kargs, 149504, stream);
}

// Round 7
// 5337.635 us; speedup vs baseline: 2.0852x; 1.1337x over previous
//
#include <hip/hip_runtime.h>
#include <hip/hip_bf16.h>

typedef _Float16 f16;
typedef _Float16 f16x8 __attribute__((ext_vector_type(8)));
typedef float f32x4 __attribute__((ext_vector_type(4)));

#define T_ 256
#define SC 2048.0f
#define INV_SC (1.0f / 2048.0f)

#define MFMA(A, B, C) __builtin_amdgcn_mfma_f32_16x16x32_f16(A, B, C, 0, 0, 0)

// ---------------------------------------------------------------------------
// Fragment layouts (all f16), unchanged from rounds 4-6:
//   A-buffers (x or h): [mt 4][ks 32][part 2][lane 64][e 8]  (256 KB / step)
//   W-buffer: [nblk 256][ks 64][part 2][lane 64][e 8]        (32 MB / layer)
//     W k 0..1023 = x-part (ks 0..31), k 1024..2047 = h-part (ks 32..63)
// ---------------------------------------------------------------------------

__global__ void prepack_x_kernel(const float* __restrict__ x, f16* __restrict__ X0) {
  unsigned int idx = blockIdx.x * 256 + threadIdx.x;  // < 33,554,432
  int e    = idx & 7;
  int l    = (idx >> 3) & 63;
  int part = (idx >> 9) & 1;
  int ks   = (idx >> 10) & 31;
  int mt   = (idx >> 15) & 3;
  int t    = idx >> 17;
  int m = mt * 16 + (l & 15);
  int k = ks * 32 + ((l >> 4) << 3) + e;
  int cc = k >> 9, kw = k & 511;
  float v = x[(((size_t)m * T_ + t) * 512 + kw) * 2 + cc];
  f16 h = (f16)v;
  X0[idx] = part ? (f16)((v - (float)h) * SC) : h;
}

__global__ void prepack_w_kernel(const float* __restrict__ Wri, const float* __restrict__ Wii,
                                 const float* __restrict__ Wrh, const float* __restrict__ Wih,
                                 f16* __restrict__ out) {
  unsigned int idx = blockIdx.x * 256 + threadIdx.x;  // < 16,777,216
  int e    = idx & 7;
  int l    = (idx >> 3) & 63;
  int part = (idx >> 9) & 1;
  int ks   = (idx >> 10) & 63;
  int nblk = idx >> 16;
  int np = nblk * 16 + (l & 15);
  int k  = ks * 32 + ((l >> 4) << 3) + e;
  int j  = np >> 3;
  int g  = (np >> 1) & 3;
  int cc = np & 1;
  int kb = k >> 9, kw = k & 511;
  size_t s = (size_t)(g * 512 + j) * 512 + kw;
  float v;
  if (cc == 0) v = (kb == 0) ? Wri[s] : (kb == 1) ? -Wii[s] : (kb == 2) ? Wrh[s] : -Wih[s];
  else         v = (kb == 0) ? Wii[s] : (kb == 1) ?  Wri[s] : (kb == 2) ? Wih[s] :  Wrh[s];
  f16 h = (f16)v;
  out[idx] = part ? (f16)((v - (float)h) * SC) : h;
}

struct PersistArgs {
  const f16* X0;      // layer-0 x frags [T][131072]
  f16* X0w;           // same buffer: layer-1 h history
  f16* ys0;           // layer-0 h frags [T][131072] (= layer-1 x input)
  const f16* W0;      // [256][65536]
  const f16* W1;
  const float *br10, *bi10, *br20, *bi20;
  const float *br11, *bi11, *br21, *bi21;
  float* y;           // (B,T,512,2)
  float* hout;        // (2,B,512,2)
  float* cout;        // (2,B,512,2)
  unsigned* flags;    // [256]
};

// 256 blocks x 1024 threads (16 waves = 4 mt x 4 kq). 1 block/CU (LDS).
// x-GEMM for step t+1 runs in spare accumulators of waves kq>=2 during the
// epilogue/flag/poll window of step t; h-GEMM is the only h_{t-1}-dependent work.
__global__ __launch_bounds__(1024) void lstm_persist(PersistArgs a) {
  extern __shared__ char smem[];
  f16* Wl = (f16*)smem;                                     // 131072 B
  float* redf = (float*)(smem + 131072);                    // [16][16][17] f32 = 17408
  volatile unsigned* goLds = (volatile unsigned*)(smem + 148480);
  float* bsum = (float*)(smem + 148484);                    // 16 f32

  int nblk = blockIdx.x;
  int tid = threadIdx.x;
  int w = tid >> 6, l = tid & 63;
  int mt = w & 3, kq = w >> 2;
  int n_loc = l & 15, r0 = (l >> 4) * 4;

  int em = tid >> 1, ejl = tid & 1;     // epilogue identity (tid<128)
  int ejg = nblk * 2 + ejl;

  if (tid == 0) *goLds = 0u;
  const f32x4 zero4 = {0.f, 0.f, 0.f, 0.f};

  for (int layer = 0; layer < 2; ++layer) {
    if (layer == 1) {
      // acquire-inv: X0 buffer is reused as layer-1 h history; kill stale lines
      (void)__hip_atomic_load(a.flags, __ATOMIC_ACQUIRE, __HIP_MEMORY_SCOPE_AGENT);
    }
    const f16* Wg = (layer ? a.W1 : a.W0) + (size_t)nblk * 65536;
    for (int i = tid * 8; i < 65536; i += 8192)
      *reinterpret_cast<f16x8*>(Wl + i) = *reinterpret_cast<const f16x8*>(Wg + i);
    if (tid < 16) {
      int jl = (tid >> 3) & 1, g = (tid >> 1) & 3, cc = tid & 1;
      int nb = g * 512 + nblk * 2 + jl;
      float b1 = cc ? (layer ? a.bi11[nb] : a.bi10[nb]) : (layer ? a.br11[nb] : a.br10[nb]);
      float b2 = cc ? (layer ? a.bi21[nb] : a.bi20[nb]) : (layer ? a.br21[nb] : a.br20[nb]);
      bsum[tid] = b1 + b2;
    }
    __syncthreads();

    const f16* AxBase = layer ? (const f16*)a.ys0 : a.X0;
    f16* Hist = layer ? a.X0w : a.ys0;

    // prime: x-GEMM for t=0 (waves kq>=2 own the x-part, 16 ks each)
    f32x4 xacc = zero4, xsacc = zero4;
    if (kq >= 2) {
      const f16* pa = AxBase + mt * 32768 + (kq - 2) * 16384 + l * 8;
      const f16* pb = Wl + (kq - 2) * 16384 + l * 8;
#pragma unroll 8
      for (int ks = 0; ks < 16; ++ks) {
        f16x8 ah = *(const f16x8*)(pa + ks * 1024);
        f16x8 al = *(const f16x8*)(pa + ks * 1024 + 512);
        f16x8 bh = *(const f16x8*)(pb + ks * 1024);
        f16x8 bl = *(const f16x8*)(pb + ks * 1024 + 512);
        xacc = MFMA(ah, bh, xacc); xsacc = MFMA(al, bh, xsacc); xsacc = MFMA(ah, bl, xsacc);
      }
    }

    float c_r = 0.f, c_i = 0.f;

    for (int t = 0; t < T_; ++t) {
      int s = layer * T_ + t;

      if (t > 0) {        // wait until all blocks published h_{t-1}
        if (w == 0) {
          const unsigned* fp = a.flags + l * 4;
          for (;;) {
            unsigned f0 = __hip_atomic_load(fp + 0, __ATOMIC_RELAXED, __HIP_MEMORY_SCOPE_AGENT);
            unsigned f1 = __hip_atomic_load(fp + 1, __ATOMIC_RELAXED, __HIP_MEMORY_SCOPE_AGENT);
            unsigned f2 = __hip_atomic_load(fp + 2, __ATOMIC_RELAXED, __HIP_MEMORY_SCOPE_AGENT);
            unsigned f3 = __hip_atomic_load(fp + 3, __ATOMIC_RELAXED, __HIP_MEMORY_SCOPE_AGENT);
            unsigned mn = min(min(f0, f1), min(f2, f3));
            if (__all(mn >= (unsigned)s)) break;
            __builtin_amdgcn_s_sleep(1);
          }
          if (l == 0) { asm volatile("" ::: "memory"); *goLds = (unsigned)s; }
        } else {
          while (*goLds < (unsigned)s) __builtin_amdgcn_s_sleep(1);
        }
        asm volatile("" ::: "memory");
      }

      f32x4 acc, sacc;
      if (kq >= 2) { acc = xacc; sacc = xsacc; }
      else         { acc = zero4; sacc = zero4; }

      if (t > 0) {        // h-GEMM: each wave adds its h-quarter (8 ks)
        const f16* pa = Hist + (size_t)(t - 1) * 131072 + mt * 32768 + kq * 8192 + l * 8;
        const f16* pb = Wl + 32768 + kq * 8192 + l * 8;
#pragma unroll
        for (int ks = 0; ks < 8; ++ks) {
          f16x8 ah = *(const f16x8*)(pa + ks * 1024);
          f16x8 al = *(const f16x8*)(pa + ks * 1024 + 512);
          f16x8 bh = *(const f16x8*)(pb + ks * 1024);
          f16x8 bl = *(const f16x8*)(pb + ks * 1024 + 512);
          acc = MFMA(ah, bh, acc); sacc = MFMA(al, bh, sacc); sacc = MFMA(ah, bl, sacc);
        }
      }
#pragma unroll
      for (int r = 0; r < 4; ++r)
        redf[((kq * 4 + mt) * 16 + n_loc) * 17 + r0 + r] = acc[r] + sacc[r] * INV_SC;
      __syncthreads();   // redf ready

      // x-prefetch for t+1 (waves kq>=2) — overlaps the epilogue below
      xacc = zero4; xsacc = zero4;
      if (kq >= 2 && t + 1 < T_) {
        const f16* pa = AxBase + (size_t)(t + 1) * 131072 + mt * 32768 + (kq - 2) * 16384 + l * 8;
        const f16* pb = Wl + (kq - 2) * 16384 + l * 8;
#pragma unroll 8
        for (int ks = 0; ks < 16; ++ks) {
          f16x8 ah = *(const f16x8*)(pa + ks * 1024);
          f16x8 al = *(const f16x8*)(pa + ks * 1024 + 512);
          f16x8 bh = *(const f16x8*)(pb + ks * 1024);
          f16x8 bl = *(const f16x8*)(pb + ks * 1024 + 512);
          xacc = MFMA(ah, bh, xacc); xsacc = MFMA(al, bh, xsacc); xsacc = MFMA(ah, bl, xsacc);
        }
      }

      float hr = 0.f, him = 0.f, cnr = 0.f, cni = 0.f;
      if (tid < 128) {
        int emt = em >> 4, eml = em & 15;
        float zr[4], zi[4];
#pragma unroll
        for (int g = 0; g < 4; ++g) {
          int nr = ejl * 8 + g * 2, ni = nr + 1;
          zr[g] = redf[((0 + emt) * 16 + nr) * 17 + eml] + redf[((4 + emt) * 16 + nr) * 17 + eml]
                + redf[((8 + emt) * 16 + nr) * 17 + eml] + redf[((12 + emt) * 16 + nr) * 17 + eml]
                + bsum[ejl * 8 + g * 2];
          zi[g] = redf[((0 + emt) * 16 + ni) * 17 + eml] + redf[((4 + emt) * 16 + ni) * 17 + eml]
                + redf[((8 + emt) * 16 + ni) * 17 + eml] + redf[((12 + emt) * 16 + ni) * 17 + eml]
                + bsum[ejl * 8 + g * 2 + 1];
        }
        float gr[4], gi[4];
#pragma unroll
        for (int g = 0; g < 4; ++g) {
          float mag = sqrtf(zr[g] * zr[g] + zi[g] * zi[g]);
          float fn = (g < 3) ? (1.f / (1.f + __expf(-mag))) : tanhf(mag);
          float sgl = fn / (mag + 1e-8f);
          gr[g] = zr[g] * sgl;
          gi[g] = zi[g] * sgl;
        }
        cnr = c_r * gr[1] + gr[0] * gr[3];
        cni = c_i * gi[1] + gi[0] * gi[3];
        c_r = cnr; c_i = cni;
        float mm = sqrtf(cnr * cnr + cni * cni);
        float sgl = tanhf(mm) / (mm + 1e-8f);
        float dr = cnr * sgl, di = cni * sgl;
        hr  = gr[2] * dr - gi[2] * di;
        him = gi[2] * dr + gr[2] * di;

        // pack h-frags: shfl_xor pairs the two j-neighbors, 2 u32 MALL stores
        f16 h0 = (f16)hr, h2 = (f16)him;
        unsigned short u0 = __builtin_bit_cast(unsigned short, h0);
        unsigned short u1 = __builtin_bit_cast(unsigned short, (f16)((hr - (float)h0) * SC));
        unsigned short u2 = __builtin_bit_cast(unsigned short, h2);
        unsigned short u3 = __builtin_bit_cast(unsigned short, (f16)((him - (float)h2) * SC));
        unsigned a1 = (unsigned)u0 | ((unsigned)u1 << 16);   // (r_hi, r_lo)
        unsigned a2 = (unsigned)u2 | ((unsigned)u3 << 16);   // (i_hi, i_lo)
        unsigned b1 = __shfl_xor(a1, 1, 64);
        unsigned b2 = __shfl_xor(a2, 1, 64);
        unsigned v0, v1;
        if (ejl == 0) { v0 = (a1 & 0xffffu) | (b1 << 16);        // plane (r,hi)
                        v1 = (a1 >> 16) | (b1 & 0xffff0000u); }  // plane (r,lo)
        else          { v0 = (b2 & 0xffffu) | (a2 << 16);        // plane (i,hi)
                        v1 = (b2 >> 16) | (a2 & 0xffff0000u); }  // plane (i,lo)
        unsigned* Y32 = (unsigned*)(Hist + (size_t)t * 131072);
        int p0 = ejl * 2;
#pragma unroll
        for (int pi = 0; pi < 2; ++pi) {
          int p = p0 + pi;
          int kbase = (p >> 1) * 512 + 2 * nblk;
          int ks2 = kbase >> 5;
          int lane_h = (em & 15) + 16 * ((kbase >> 3) & 3);
          int idxf = (((em >> 4) * 32 + ks2) * 2 + (p & 1)) * 512 + lane_h * 8 + (kbase & 7);
          __hip_atomic_store(&Y32[idxf >> 1], pi ? v1 : v0,
                             __ATOMIC_RELAXED, __HIP_MEMORY_SCOPE_AGENT);
        }
      }
      asm volatile("s_waitcnt vmcnt(0)" ::: "memory");  // drain h-stores (wave-wide)
      __syncthreads();   // all h-stores drained, x-prefetch done
      if (tid == 0 && s + 1 < 2 * T_)
        __hip_atomic_store(&a.flags[nblk], (unsigned)(s + 1),
                           __ATOMIC_RELAXED, __HIP_MEMORY_SCOPE_AGENT);

      // deferred fp32 outputs — off the critical path, drain during next poll
      if (tid < 128) {
        if (layer == 1) {
          float2 yv; yv.x = hr; yv.y = him;
          *reinterpret_cast<float2*>(a.y + (((size_t)em * T_ + t) * 512 + ejg) * 2) = yv;
        }
        if (t == T_ - 1) {
          float* hp = a.hout + (size_t)layer * 65536 + ((size_t)em * 512 + ejg) * 2;
          hp[0] = hr; hp[1] = him;
          float* cq = a.cout + (size_t)layer * 65536 + ((size_t)em * 512 + ejg) * 2;
          cq[0] = cnr; cq[1] = cni;
        }
      }
    } // t
  } // layer
}

extern "C" void kernel_launch(void* const* d_in, const int* in_sizes, int n_in,
                              void* d_out, int out_size, void* d_ws, size_t ws_size,
                              hipStream_t stream) {
  const float* x = (const float*)d_in[0];
  char* ws = (char*)d_ws;
  f16* X0    = (f16*)(ws + 0);                     //  64 MB
  f16* ys0   = (f16*)(ws + (size_t)67108864);      //  64 MB
  f16* W0    = (f16*)(ws + (size_t)134217728);     //  32 MB
  f16* W1    = (f16*)(ws + (size_t)167772160);     //  32 MB
  unsigned* flags = (unsigned*)(ws + (size_t)201326592);  // 1 KB

  hipMemsetAsync(ws + 201326592, 0, 1024, stream);

  prepack_x_kernel<<<131072, 256, 0, stream>>>(x, X0);
  prepack_w_kernel<<<65536, 256, 0, stream>>>((const float*)d_in[1], (const float*)d_in[2],
                                              (const float*)d_in[5], (const float*)d_in[6], W0);
  prepack_w_kernel<<<65536, 256, 0, stream>>>((const float*)d_in[9], (const float*)d_in[10],
                                              (const float*)d_in[13], (const float*)d_in[14], W1);

  float* y = (float*)d_out;
  PersistArgs pa;
  pa.X0 = X0; pa.X0w = X0; pa.ys0 = ys0;
  pa.W0 = W0; pa.W1 = W1;
  pa.br10 = (const float*)d_in[3];  pa.bi10 = (const float*)d_in[4];
  pa.br20 = (const float*)d_in[7];  pa.bi20 = (const float*)d_in[8];
  pa.br11 = (const float*)d_in[11]; pa.bi11 = (const float*)d_in[12];
  pa.br21 = (const float*)d_in[15]; pa.bi21 = (const float*)d_in[16];
  pa.y = y; pa.hout = y + 16777216; pa.cout = y + 16777216 + 131072;
  pa.flags = flags;

  static bool attr_set = false;
  if (!attr_set) {
    hipFuncSetAttribute((const void*)lstm_persist,
                        hipFuncAttributeMaxDynamicSharedMemorySize, 148608);
    attr_set = true;
  }
  void* kargs[] = { &pa };
  hipLaunchCooperativeKernel((const void*)lstm_persist, dim3(256), dim3(1024),
                             kargs, 148608, stream);
}

// Round 8
// 4158.017 us; speedup vs baseline: 2.6767x; 1.2837x over previous
//
#include <hip/hip_runtime.h>
#include <hip/hip_bf16.h>

typedef _Float16 f16;
typedef _Float16 f16x8 __attribute__((ext_vector_type(8)));
typedef float f32x4 __attribute__((ext_vector_type(4)));

#define T_ 256
#define SC 2048.0f
#define INV_SC (1.0f / 2048.0f)
#define RMASK 15          // 16-slot rings for recurrent h buffers
#define MFMA(A, B, C) __builtin_amdgcn_mfma_f32_16x16x32_f16(A, B, C, 0, 0, 0)

// ---------------------------------------------------------------------------
// A-buffers (x or h frags): [mt 4][ks 32][part 2][lane 64][e 8] f16 (256 KB/step)
//   element = A[mt*16+(l&15)][ks*32+(l>>4)*8+e], part 0 = hi, 1 = lo*SC
// W pack per layer: [which 2 (hi/lo)][jb 128][nt 2][ks 64][lane 64][e 8] f16
//   row n' = jb*32 + nt*16 + (l&15)  (j-major: n' = (j*4+g)*2+cc)
//   k = ks*32 + (l>>4)*8 + e over [xr|xi|hr|hi] segments of 512
// ---------------------------------------------------------------------------

__global__ void prepack_x_kernel(const float* __restrict__ x, f16* __restrict__ X0) {
  unsigned int idx = blockIdx.x * 256 + threadIdx.x;  // < 33,554,432
  int e    = idx & 7;
  int l    = (idx >> 3) & 63;
  int part = (idx >> 9) & 1;
  int ks   = (idx >> 10) & 31;
  int mt   = (idx >> 15) & 3;
  int t    = idx >> 17;
  int m = mt * 16 + (l & 15);
  int k = ks * 32 + ((l >> 4) << 3) + e;
  int cc = k >> 9, kw = k & 511;
  float v = x[(((size_t)m * T_ + t) * 512 + kw) * 2 + cc];
  f16 h = (f16)v;
  X0[idx] = part ? (f16)((v - (float)h) * SC) : h;
}

__global__ void prepack_w_kernel(const float* __restrict__ Wri, const float* __restrict__ Wii,
                                 const float* __restrict__ Wrh, const float* __restrict__ Wih,
                                 f16* __restrict__ out) {
  unsigned int idx = blockIdx.x * 256 + threadIdx.x;  // < 16,777,216
  int e     = idx & 7;
  int l     = (idx >> 3) & 63;
  int ks    = (idx >> 9) & 63;
  int nt    = (idx >> 15) & 1;
  int jb    = (idx >> 16) & 127;
  int which = idx >> 23;
  int n_local = nt * 16 + (l & 15);
  int np = jb * 32 + n_local;
  int j  = np >> 3;
  int g  = (np >> 1) & 3;
  int cc = np & 1;
  int k  = ks * 32 + ((l >> 4) << 3) + e;
  int kb = k >> 9, kw = k & 511;
  size_t s = (size_t)(g * 512 + j) * 512 + kw;
  float v;
  if (cc == 0) v = (kb == 0) ? Wri[s] : (kb == 1) ? -Wii[s] : (kb == 2) ? Wrh[s] : -Wih[s];
  else         v = (kb == 0) ? Wii[s] : (kb == 1) ?  Wri[s] : (kb == 2) ? Wih[s] :  Wrh[s];
  f16 h = (f16)v;
  out[idx] = which ? (f16)((v - (float)h) * SC) : h;
}

struct PersistArgs {
  const f16* X0;      // [T][131072] layer-0 x frags
  f16* ys0;           // 16-slot ring [16][131072]: layer-0 h frags
  f16* h1;            // 16-slot ring: layer-1 h frags
  const f16* Wpk0;    // [2][128][65536] (hi | lo)
  const f16* Wpk1;
  const float *br10, *bi10, *br20, *bi20;
  const float *br11, *bi11, *br21, *bi21;
  float* y;           // (B,T,512,2)
  float* hout;        // (2,B,512,2)
  float* cout;        // (2,B,512,2)
  unsigned* flags;    // [256]
};

// 256 blocks x 1024 threads; blocks 128/layer (lay = (bid>>3)&1), 4 hidden j each.
// Stage s (0..256): L0 computes step s (s<256); L1 computes step s-1 (s>=1).
// Waves: 16 = 4 mt x 4 kq (kq 0,1 = x-half of K, kq 2,3 = h-half); both n-tiles
// per wave; redf reduced pairwise (kq even write, kq odd RMW).
__global__ __launch_bounds__(1024, 4) void lstm_persist(PersistArgs a) {
  extern __shared__ char smem[];
  f16* Wl = (f16*)smem;                                  // W-hi slice 131072 B
  float* redf = (float*)(smem + 131072);                 // [2][4][2][16][17] f32 = 17408 B
  volatile unsigned* goLds = (volatile unsigned*)(smem + 148480);

  int bid = blockIdx.x;
  int xcd = bid & 7, rr = bid >> 3;
  int lay = rr & 1;
  int jb = (rr >> 1) * 8 + xcd;       // 0..127
  int tid = threadIdx.x;
  int w = tid >> 6, l = tid & 63;
  int mt = w & 3, kq = w >> 2;
  int n_loc = l & 15, r0 = (l >> 4) * 4;

  // epilogue identity (tid < 256): one (m, j-local) pair
  int em = tid >> 2, ejl = tid & 3;
  int emt = em >> 4, eml = em & 15;
  int jg = jb * 4 + ejl;

  const f16* Wpk = lay ? a.Wpk1 : a.Wpk0;
  const f16* WhiG = Wpk + (size_t)jb * 65536;
  const f16* WloG = Wpk + 8388608 + (size_t)jb * 65536;
  for (int i = tid * 8; i < 65536; i += 8192)
    *reinterpret_cast<f16x8*>(Wl + i) = *reinterpret_cast<const f16x8*>(WhiG + i);
  if (tid == 0) *goLds = 0u;

  // bias sums into registers (meaningful for tid<256 only)
  float bsr[4], bsi[4];
  {
    const float* br1 = lay ? a.br11 : a.br10;
    const float* bi1 = lay ? a.bi11 : a.bi10;
    const float* br2 = lay ? a.br21 : a.br20;
    const float* bi2 = lay ? a.bi21 : a.bi20;
#pragma unroll
    for (int g = 0; g < 4; ++g) {
      int nb = g * 512 + jg;
      bsr[g] = br1[nb] + br2[nb];
      bsi[g] = bi1[nb] + bi2[nb];
    }
  }
  __syncthreads();

  float c_r = 0.f, c_i = 0.f;

  for (int s = 0; s <= T_; ++s) {
    if (s > 0) {   // wait: all blocks published stage s-1
      if (w == 0) {
        const unsigned* fp = a.flags + l * 4;
        for (;;) {
          unsigned f0 = __hip_atomic_load(fp + 0, __ATOMIC_RELAXED, __HIP_MEMORY_SCOPE_AGENT);
          unsigned f1 = __hip_atomic_load(fp + 1, __ATOMIC_RELAXED, __HIP_MEMORY_SCOPE_AGENT);
          unsigned f2 = __hip_atomic_load(fp + 2, __ATOMIC_RELAXED, __HIP_MEMORY_SCOPE_AGENT);
          unsigned f3 = __hip_atomic_load(fp + 3, __ATOMIC_RELAXED, __HIP_MEMORY_SCOPE_AGENT);
          unsigned mn = min(min(f0, f1), min(f2, f3));
          if (__all(mn >= (unsigned)s)) break;
          __builtin_amdgcn_s_sleep(1);
        }
        if (l == 0) { asm volatile("" ::: "memory"); *goLds = (unsigned)s; }
      } else {
        while (*goLds < (unsigned)s) __builtin_amdgcn_s_sleep(1);
      }
      asm volatile("" ::: "memory");
    }

    bool active = lay ? (s >= 1) : (s < T_);
    int t = lay ? (s - 1) : s;

    f32x4 comb0 = {0.f, 0.f, 0.f, 0.f}, comb1 = {0.f, 0.f, 0.f, 0.f};
    int rb0 = 0, rb1 = 0;
    if (active) {
      f32x4 acc0 = {0,0,0,0}, acc1 = {0,0,0,0}, sacc0 = {0,0,0,0}, sacc1 = {0,0,0,0};
      bool hwave = (kq >= 2);
      if (!hwave || t > 0) {
        const f16* Ab;
        if (hwave)
          Ab = (lay ? a.h1 : a.ys0) + (size_t)((t - 1) & RMASK) * 131072;
        else
          Ab = lay ? (a.ys0 + (size_t)(t & RMASK) * 131072)
                   : (a.X0 + (size_t)t * 131072);
        int ksl = (kq & 1) * 16;       // local ks within the x- or h-buffer
        int ksg = kq * 16;             // global ks 0..63 into W
        const f16* pa = Ab + mt * 32768 + ksl * 1024 + l * 8;
        const f16* pw = Wl + ksg * 512 + l * 8;
        const f16* po = WloG + ksg * 512 + l * 8;
#pragma unroll 4
        for (int i = 0; i < 16; ++i) {
          f16x8 ah = *reinterpret_cast<const f16x8*>(pa + i * 1024);
          f16x8 al = *reinterpret_cast<const f16x8*>(pa + i * 1024 + 512);
          f16x8 w0 = *reinterpret_cast<const f16x8*>(pw + i * 512);
          f16x8 w1 = *reinterpret_cast<const f16x8*>(pw + 32768 + i * 512);
          f16x8 o0 = *reinterpret_cast<const f16x8*>(po + i * 512);
          f16x8 o1 = *reinterpret_cast<const f16x8*>(po + 32768 + i * 512);
          acc0 = MFMA(ah, w0, acc0); sacc0 = MFMA(al, w0, sacc0); sacc0 = MFMA(ah, o0, sacc0);
          acc1 = MFMA(ah, w1, acc1); sacc1 = MFMA(al, w1, sacc1); sacc1 = MFMA(ah, o1, sacc1);
        }
      }
      comb0 = acc0 + sacc0 * INV_SC;
      comb1 = acc1 + sacc1 * INV_SC;
      rb0 = (((kq >> 1) * 4 + mt) * 2 + 0) * 272 + n_loc * 17 + r0;
      rb1 = (((kq >> 1) * 4 + mt) * 2 + 1) * 272 + n_loc * 17 + r0;
      if ((kq & 1) == 0) {
#pragma unroll
        for (int q = 0; q < 4; ++q) { redf[rb0 + q] = comb0[q]; redf[rb1 + q] = comb1[q]; }
      }
    }
    __syncthreads();
    if (active && (kq & 1)) {
#pragma unroll
      for (int q = 0; q < 4; ++q) { redf[rb0 + q] += comb0[q]; redf[rb1 + q] += comb1[q]; }
    }
    __syncthreads();

    float hr = 0.f, him = 0.f, cnr = 0.f, cni = 0.f;
    if (active && tid < 256) {
      float zr[4], zi[4];
#pragma unroll
      for (int g = 0; g < 4; ++g) {
        int nl = ejl * 8 + g * 2;
        int nt_ = nl >> 4, nn = nl & 15;
        int i0 = (emt * 2 + nt_) * 272 + nn * 17 + eml;
        int i1 = ((4 + emt) * 2 + nt_) * 272 + nn * 17 + eml;
        zr[g] = redf[i0] + redf[i1] + bsr[g];
        zi[g] = redf[i0 + 17] + redf[i1 + 17] + bsi[g];
      }
      float gr[4], gi[4];
#pragma unroll
      for (int g = 0; g < 4; ++g) {
        float mag = sqrtf(zr[g] * zr[g] + zi[g] * zi[g]);
        float fn = (g < 3) ? (1.f / (1.f + __expf(-mag))) : tanhf(mag);
        float sg = fn / (mag + 1e-8f);
        gr[g] = zr[g] * sg;
        gi[g] = zi[g] * sg;
      }
      cnr = c_r * gr[1] + gr[0] * gr[3];
      cni = c_i * gi[1] + gi[0] * gi[3];
      c_r = cnr; c_i = cni;
      float mm = sqrtf(cnr * cnr + cni * cni);
      float sg = tanhf(mm) / (mm + 1e-8f);
      float dr = cnr * sg, di = cni * sg;
      hr  = gr[2] * dr - gi[2] * di;
      him = gi[2] * dr + gr[2] * di;

      // pack h-frags pairwise (j, j^1) and store 2 u32 via MALL
      f16 h0 = (f16)hr, h2 = (f16)him;
      unsigned a1 = (unsigned)__builtin_bit_cast(unsigned short, h0)
                  | ((unsigned)__builtin_bit_cast(unsigned short, (f16)((hr - (float)h0) * SC)) << 16);
      unsigned a2 = (unsigned)__builtin_bit_cast(unsigned short, h2)
                  | ((unsigned)__builtin_bit_cast(unsigned short, (f16)((him - (float)h2) * SC)) << 16);
      unsigned b1 = __shfl_xor(a1, 1, 64);
      unsigned b2 = __shfl_xor(a2, 1, 64);
      unsigned v0, v1; int kbase;
      int p = ejl >> 1;
      if ((ejl & 1) == 0) {
        v0 = (a1 & 0xffffu) | (b1 << 16);
        v1 = (a1 >> 16) | (b1 & 0xffff0000u);
        kbase = jb * 4 + 2 * p;               // real planes
      } else {
        v0 = (b2 & 0xffffu) | (a2 << 16);
        v1 = (b2 >> 16) | (a2 & 0xffff0000u);
        kbase = 512 + jb * 4 + 2 * p;         // imag planes
      }
      f16* Yb = (lay ? a.h1 : a.ys0) + (size_t)(t & RMASK) * 131072;
      unsigned* Y32 = (unsigned*)Yb;
      int ks2 = kbase >> 5;
      int lane_h = eml + 16 * ((kbase >> 3) & 3);
      int e0 = kbase & 7;
      int idx0 = ((emt * 32 + ks2) * 2 + 0) * 512 + lane_h * 8 + e0;
      int idx1 = ((emt * 32 + ks2) * 2 + 1) * 512 + lane_h * 8 + e0;
      __hip_atomic_store(&Y32[idx0 >> 1], v0, __ATOMIC_RELAXED, __HIP_MEMORY_SCOPE_AGENT);
      __hip_atomic_store(&Y32[idx1 >> 1], v1, __ATOMIC_RELAXED, __HIP_MEMORY_SCOPE_AGENT);
    }

    asm volatile("s_waitcnt vmcnt(0)" ::: "memory");   // drain h-stores (per-wave)
    __syncthreads();
    if (tid == 0 && s < T_)
      __hip_atomic_store(&a.flags[bid], (unsigned)(s + 1),
                         __ATOMIC_RELAXED, __HIP_MEMORY_SCOPE_AGENT);

    // deferred fp32 outputs — off the flag path, drain during next poll
    if (active && tid < 256) {
      if (lay) {
        float2 yv; yv.x = hr; yv.y = him;
        *reinterpret_cast<float2*>(a.y + (((size_t)em * T_ + t) * 512 + jg) * 2) = yv;
      }
      if (t == T_ - 1) {
        float* hp = a.hout + (size_t)lay * 65536 + ((size_t)em * 512 + jg) * 2;
        hp[0] = hr; hp[1] = him;
        float* cq = a.cout + (size_t)lay * 65536 + ((size_t)em * 512 + jg) * 2;
        cq[0] = cnr; cq[1] = cni;
      }
    }
  }
}

extern "C" void kernel_launch(void* const* d_in, const int* in_sizes, int n_in,
                              void* d_out, int out_size, void* d_ws, size_t ws_size,
                              hipStream_t stream) {
  const float* x = (const float*)d_in[0];
  char* ws = (char*)d_ws;
  f16* X0   = (f16*)(ws + 0);                          //  64 MB
  f16* Wpk0 = (f16*)(ws + (size_t)67108864);           //  32 MB
  f16* Wpk1 = (f16*)(ws + (size_t)100663296);          //  32 MB
  f16* ys0  = (f16*)(ws + (size_t)134217728);          //   4 MB ring
  f16* h1   = (f16*)(ws + (size_t)138412032);          //   4 MB ring
  unsigned* flags = (unsigned*)(ws + (size_t)142606336);  // 1 KB

  hipMemsetAsync(ws + 142606336, 0, 1024, stream);

  prepack_x_kernel<<<131072, 256, 0, stream>>>(x, X0);
  prepack_w_kernel<<<65536, 256, 0, stream>>>((const float*)d_in[1], (const float*)d_in[2],
                                              (const float*)d_in[5], (const float*)d_in[6], Wpk0);
  prepack_w_kernel<<<65536, 256, 0, stream>>>((const float*)d_in[9], (const float*)d_in[10],
                                              (const float*)d_in[13], (const float*)d_in[14], Wpk1);

  float* y = (float*)d_out;
  PersistArgs pa;
  pa.X0 = X0; pa.ys0 = ys0; pa.h1 = h1;
  pa.Wpk0 = Wpk0; pa.Wpk1 = Wpk1;
  pa.br10 = (const float*)d_in[3];  pa.bi10 = (const float*)d_in[4];
  pa.br20 = (const float*)d_in[7];  pa.bi20 = (const float*)d_in[8];
  pa.br11 = (const float*)d_in[11]; pa.bi11 = (const float*)d_in[12];
  pa.br21 = (const float*)d_in[15]; pa.bi21 = (const float*)d_in[16];
  pa.y = y; pa.hout = y + 16777216; pa.cout = y + 16777216 + 131072;
  pa.flags = flags;

  hipFuncSetAttribute((const void*)lstm_persist,
                      hipFuncAttributeMaxDynamicSharedMemorySize, 148608);
  void* kargs[] = { &pa };
  hipLaunchCooperativeKernel((const void*)lstm_persist, dim3(256), dim3(1024),
                             kargs, 148608, stream);
}